// Round 4
// baseline (206.535 us; speedup 1.0000x reference)
//
#include <hip/hip_runtime.h>
#include <hip/hip_cooperative_groups.h>

namespace cg = cooperative_groups;

typedef float f32x4 __attribute__((ext_vector_type(4)));

constexpr int IN_F  = 8192;
constexpr int OUT_F = 8192;
constexpr int BATCH = 4096;
constexpr int TPB   = 256;

// ---- cooperative (fused) config: 512 blocks = 2/CU, 2x occupancy margin ----
constexpr int NBLK_C   = 512;
constexpr int COLGRP   = 8;                    // 8 groups x 256 float4 = 8192 cols
constexpr int CHUNKS_C = NBLK_C / COLGRP;      // 64 row-chunks
constexpr int RPC_C    = OUT_F / CHUNKS_C;     // 128 rows per chunk
constexpr int ROWS_C   = BATCH / NBLK_C;       // 8 batch rows per block (phase 3)

// out[b] = ( dot(x[b,:], wsum) + bsum ) / OUT_F, wsum[i] = sum_o W[o,i]
__global__ __launch_bounds__(TPB, 4) void fused_kernel(
    const float* __restrict__ x, const float* __restrict__ W,
    const float* __restrict__ bias, float* __restrict__ out,
    float* __restrict__ part, float* __restrict__ wsum,
    float* __restrict__ bsum) {

    __shared__ float lds_w[IN_F];   // 32 KB
    __shared__ float red[8];
    const int tid = threadIdx.x, blk = blockIdx.x;

    // ---- Phase 1: partial column sums of W (streamed, coalesced) ----
    {
        const int  col4  = (blk & (COLGRP - 1)) * TPB + tid;
        const int  chunk = blk >> 3;
        const f32x4* __restrict__ p =
            reinterpret_cast<const f32x4*>(W) + (long)chunk * RPC_C * (IN_F / 4) + col4;
        f32x4 acc = {0.f, 0.f, 0.f, 0.f};
        #pragma unroll 8
        for (int r = 0; r < RPC_C; ++r)
            acc += __builtin_nontemporal_load(&p[(long)r * (IN_F / 4)]);
        reinterpret_cast<f32x4*>(part)[(long)chunk * (IN_F / 4) + col4] = acc;
    }

    cg::this_grid().sync();

    // ---- Phase 2: combine partials -> wsum; block 32 reduces bias ----
    if (blk < 32) {
        const int col = blk * TPB + tid;
        float s = 0.f;
        #pragma unroll 8
        for (int c = 0; c < CHUNKS_C; ++c) s += part[(long)c * IN_F + col];
        wsum[col] = s;
    } else if (blk == 32) {
        float bs = 0.f;
        for (int k = tid; k < OUT_F; k += TPB) bs += bias[k];
        #pragma unroll
        for (int o = 32; o; o >>= 1) bs += __shfl_down(bs, o);
        if ((tid & 63) == 0) red[tid >> 6] = bs;
        __syncthreads();   // block-uniform branch: safe
        if (tid == 0) *bsum = red[0] + red[1] + red[2] + red[3];
    }

    cg::this_grid().sync();

    // ---- Phase 3: LDS-stage wsum; 8 rows/block interleaved dot ----
    {
        f32x4* lw4 = reinterpret_cast<f32x4*>(lds_w);
        const f32x4* gw4 = reinterpret_cast<const f32x4*>(wsum);
        #pragma unroll
        for (int k = tid; k < IN_F / 4; k += TPB) lw4[k] = gw4[k];
        __syncthreads();

        const long rowbase = (long)blk * ROWS_C;
        const f32x4* __restrict__ x4 =
            reinterpret_cast<const f32x4*>(x) + rowbase * (IN_F / 4);
        float s[ROWS_C] = {};
        for (int k = tid; k < IN_F / 4; k += TPB) {
            f32x4 wv = lw4[k];
            #pragma unroll
            for (int r = 0; r < ROWS_C; ++r) {   // static indices only (rule #20)
                f32x4 xv = __builtin_nontemporal_load(&x4[(long)r * (IN_F / 4) + k]);
                s[r] += xv.x * wv.x + xv.y * wv.y + xv.z * wv.z + xv.w * wv.w;
            }
        }
        float bsv = (tid == 0) ? *bsum : 0.f;
        #pragma unroll
        for (int r = 0; r < ROWS_C; ++r) {
            float v = s[r];
            #pragma unroll
            for (int o = 32; o; o >>= 1) v += __shfl_down(v, o);
            if ((tid & 63) == 0) red[tid >> 6] = v;
            __syncthreads();
            if (tid == 0)
                out[rowbase + r] = (red[0] + red[1] + red[2] + red[3] + bsv) * (1.0f / OUT_F);
            __syncthreads();
        }
    }
}

// ---------------- fallback: tuned 3-kernel path (known-good structure) ------
__global__ __launch_bounds__(TPB) void colsum_partial_kernel(
    const float* __restrict__ W, float* __restrict__ part, int rowsPerChunk) {
    const int col4 = blockIdx.x * TPB + threadIdx.x;
    const long row0 = (long)blockIdx.y * rowsPerChunk;
    const f32x4* __restrict__ p =
        reinterpret_cast<const f32x4*>(W) + row0 * (IN_F / 4) + col4;
    f32x4 acc = {0.f, 0.f, 0.f, 0.f};
    #pragma unroll 8
    for (int r = 0; r < rowsPerChunk; ++r)
        acc += __builtin_nontemporal_load(&p[(long)r * (IN_F / 4)]);
    reinterpret_cast<f32x4*>(part)[(long)blockIdx.y * (IN_F / 4) + col4] = acc;
}

__global__ __launch_bounds__(TPB) void combine_kernel(
    const float* __restrict__ part, const float* __restrict__ bias,
    float* __restrict__ wsum, float* __restrict__ bsum, int chunks) {
    const int blk = blockIdx.x, tid = threadIdx.x;
    if (blk < 32) {
        const int col = blk * TPB + tid;
        float s = 0.f;
        for (int c = 0; c < chunks; ++c) s += part[(long)c * IN_F + col];
        wsum[col] = s;
    } else {
        __shared__ float red[4];
        float bs = 0.f;
        for (int k = tid; k < OUT_F; k += TPB) bs += bias[k];
        #pragma unroll
        for (int o = 32; o; o >>= 1) bs += __shfl_down(bs, o);
        if ((tid & 63) == 0) red[tid >> 6] = bs;
        __syncthreads();
        if (tid == 0) *bsum = red[0] + red[1] + red[2] + red[3];
    }
}

constexpr int NBLK_R = 1024;
constexpr int ROWS_R = BATCH / NBLK_R;   // 4

__global__ __launch_bounds__(TPB) void rowdot_kernel(
    const float* __restrict__ x, const float* __restrict__ wsum,
    const float* __restrict__ bsum, float* __restrict__ out) {
    __shared__ float lds_w[IN_F];
    __shared__ float red[8];
    const int tid = threadIdx.x;
    f32x4* lw4 = reinterpret_cast<f32x4*>(lds_w);
    const f32x4* gw4 = reinterpret_cast<const f32x4*>(wsum);
    #pragma unroll
    for (int k = tid; k < IN_F / 4; k += TPB) lw4[k] = gw4[k];
    __syncthreads();

    const long rowbase = (long)blockIdx.x * ROWS_R;
    const f32x4* __restrict__ x4 =
        reinterpret_cast<const f32x4*>(x) + rowbase * (IN_F / 4);
    float s[ROWS_R] = {};
    for (int k = tid; k < IN_F / 4; k += TPB) {
        f32x4 wv = lw4[k];
        #pragma unroll
        for (int r = 0; r < ROWS_R; ++r) {
            f32x4 xv = __builtin_nontemporal_load(&x4[(long)r * (IN_F / 4) + k]);
            s[r] += xv.x * wv.x + xv.y * wv.y + xv.z * wv.z + xv.w * wv.w;
        }
    }
    float bsv = (tid == 0) ? *bsum : 0.f;
    #pragma unroll
    for (int r = 0; r < ROWS_R; ++r) {
        float v = s[r];
        #pragma unroll
        for (int o = 32; o; o >>= 1) v += __shfl_down(v, o);
        if ((tid & 63) == 0) red[tid >> 6] = v;
        __syncthreads();
        if (tid == 0)
            out[rowbase + r] = (red[0] + red[1] + red[2] + red[3] + bsv) * (1.0f / OUT_F);
        __syncthreads();
    }
}

extern "C" void kernel_launch(void* const* d_in, const int* in_sizes, int n_in,
                              void* d_out, int out_size, void* d_ws, size_t ws_size,
                              hipStream_t stream) {
    const float* x    = (const float*)d_in[0];
    const float* W    = (const float*)d_in[1];
    const float* bias = (const float*)d_in[2];
    float*       out  = (float*)d_out;

    // ws layout sized by the larger (fallback) chunk count; both paths share it.
    int chunksFB = 256;
    while (chunksFB > CHUNKS_C &&
           ((size_t)chunksFB * IN_F + IN_F + 16) * sizeof(float) > ws_size)
        chunksFB >>= 1;
    float* part = (float*)d_ws;
    float* wsum = part + (size_t)chunksFB * IN_F;
    float* bsum = wsum + IN_F;

    // Capture-safe host queries (no allocation, no stream ops) -> deterministic path choice.
    int dev = 0;    (void)hipGetDevice(&dev);
    int coop = 0;   (void)hipDeviceGetAttribute(&coop, hipDeviceAttributeCooperativeLaunch, dev);
    int ncu = 0;    (void)hipDeviceGetAttribute(&ncu, hipDeviceAttributeMultiprocessorCount, dev);
    int maxblk = 0;
    (void)hipOccupancyMaxActiveBlocksPerMultiprocessor(&maxblk, fused_kernel, TPB, 0);

    if (coop && (long)maxblk * ncu >= NBLK_C) {
        void* args[] = {(void*)&x, (void*)&W, (void*)&bias, (void*)&out,
                        (void*)&part, (void*)&wsum, (void*)&bsum};
        hipError_t err = hipLaunchCooperativeKernel(
            (const void*)fused_kernel, dim3(NBLK_C), dim3(TPB), args, 0, stream);
        if (err == hipSuccess) return;
        // else fall through to the 3-kernel path
    }

    const int rowsPerChunk = OUT_F / chunksFB;
    colsum_partial_kernel<<<dim3(IN_F / (TPB * 4), chunksFB), TPB, 0, stream>>>(
        W, part, rowsPerChunk);
    combine_kernel<<<33, TPB, 0, stream>>>(part, bias, wsum, bsum, chunksFB);
    rowdot_kernel<<<NBLK_R, TPB, 0, stream>>>(x, wsum, bsum, out);
}

// Round 5
// 100.735 us; speedup vs baseline: 2.0503x; 2.0503x over previous
//
#include <hip/hip_runtime.h>

typedef float f32x4 __attribute__((ext_vector_type(4)));

constexpr int IN_F  = 8192;
constexpr int OUT_F = 8192;
constexpr int BATCH = 4096;
constexpr int TPB   = 256;

constexpr int COLG = IN_F / (TPB * 4);   // 8 column-groups of 1024 floats

// ---------------------------------------------------------------------------
// Kernel A: partial column sums of W.  grid = (8, chunks), block = 256.
//   Block (cg, ch) sums rows [ch*RPC, (ch+1)*RPC) of 1024 consecutive columns.
//   Plain (cacheable) loads: Infinity Cache retains ~180 MB of W across
//   graph replays — NT loads measurably suppressed that (R4: 1 TB/s).
// ---------------------------------------------------------------------------
__global__ __launch_bounds__(TPB) void colsum_kernel(
    const float* __restrict__ W, float* __restrict__ part, int rpc) {
    const int col4 = blockIdx.x * TPB + threadIdx.x;          // float4 col
    const f32x4* __restrict__ p = reinterpret_cast<const f32x4*>(W)
        + (long)blockIdx.y * rpc * (IN_F / 4) + col4;
    f32x4 acc = {0.f, 0.f, 0.f, 0.f};
    #pragma unroll 8
    for (int r = 0; r < rpc; ++r)
        acc += p[(long)r * (IN_F / 4)];
    reinterpret_cast<f32x4*>(part)[(long)blockIdx.y * (IN_F / 4) + col4] = acc;
}

// ---------------------------------------------------------------------------
// Kernel B: combine chunk partials -> wsum; block 32 reduces bias -> bsum.
//   grid = 33, block = 256. Fixed summation order: deterministic.
// ---------------------------------------------------------------------------
__global__ __launch_bounds__(TPB) void combine_kernel(
    const float* __restrict__ part, const float* __restrict__ bias,
    float* __restrict__ wsum, float* __restrict__ bsum, int chunks) {
    const int blk = blockIdx.x, tid = threadIdx.x;
    if (blk < 32) {
        const int col = blk * TPB + tid;
        float s = 0.f;
        #pragma unroll 8
        for (int c = 0; c < chunks; ++c) s += part[(long)c * IN_F + col];
        wsum[col] = s;
    } else {
        __shared__ float red[4];
        float bs = 0.f;
        for (int k = tid; k < OUT_F; k += TPB) bs += bias[k];
        #pragma unroll
        for (int o = 32; o; o >>= 1) bs += __shfl_down(bs, o);
        if ((tid & 63) == 0) red[tid >> 6] = bs;
        __syncthreads();
        if (tid == 0) *bsum = red[0] + red[1] + red[2] + red[3];
    }
}

// ---------------------------------------------------------------------------
// Kernel C: out[b] = (dot(x[b,:], wsum) + bsum) / OUT_F
//   grid = 2048 (8 blocks/CU), 2 rows per block. wsum (32 KB) is read from
//   global — it is L1/L2-resident (don't LDS-stage cache-fit data; the LDS
//   copy was capping occupancy).
// ---------------------------------------------------------------------------
constexpr int NBLK_R = 2048;
constexpr int ROWS_R = BATCH / NBLK_R;   // 2

__global__ __launch_bounds__(TPB) void rowdot_kernel(
    const float* __restrict__ x, const float* __restrict__ wsum,
    const float* __restrict__ bsum, float* __restrict__ out) {
    __shared__ float red[8];
    const int tid = threadIdx.x;
    const long rowbase = (long)blockIdx.x * ROWS_R;
    const f32x4* __restrict__ x4 =
        reinterpret_cast<const f32x4*>(x) + rowbase * (IN_F / 4);
    const f32x4* __restrict__ w4 = reinterpret_cast<const f32x4*>(wsum);

    float s0 = 0.f, s1 = 0.f;
    #pragma unroll
    for (int k = tid; k < IN_F / 4; k += TPB) {     // 8 iterations, fully unrolled
        f32x4 wv = w4[k];
        f32x4 a  = x4[k];
        f32x4 b  = x4[(IN_F / 4) + k];
        s0 += a.x * wv.x + a.y * wv.y + a.z * wv.z + a.w * wv.w;
        s1 += b.x * wv.x + b.y * wv.y + b.z * wv.z + b.w * wv.w;
    }
    #pragma unroll
    for (int o = 32; o; o >>= 1) {
        s0 += __shfl_down(s0, o);
        s1 += __shfl_down(s1, o);
    }
    const int wid = tid >> 6;
    if ((tid & 63) == 0) { red[wid] = s0; red[4 + wid] = s1; }
    __syncthreads();
    if (tid == 0) {
        const float bsv = *bsum;
        out[rowbase]     = (red[0] + red[1] + red[2] + red[3] + bsv) * (1.0f / OUT_F);
        out[rowbase + 1] = (red[4] + red[5] + red[6] + red[7] + bsv) * (1.0f / OUT_F);
    }
}

extern "C" void kernel_launch(void* const* d_in, const int* in_sizes, int n_in,
                              void* d_out, int out_size, void* d_ws, size_t ws_size,
                              hipStream_t stream) {
    const float* x    = (const float*)d_in[0];  // [BATCH, IN_F]
    const float* W    = (const float*)d_in[1];  // [OUT_F, IN_F]
    const float* bias = (const float*)d_in[2];  // [OUT_F]
    float*       out  = (float*)d_out;          // [BATCH]

    // ws: [chunks][IN_F] partials | [IN_F] wsum | [1] bsum
    int chunks = 256;                            // 2048 streaming blocks in A
    while (chunks > 1 &&
           ((size_t)chunks * IN_F + IN_F + 16) * sizeof(float) > ws_size)
        chunks >>= 1;
    const int rpc = OUT_F / chunks;

    float* part = (float*)d_ws;
    float* wsum = part + (size_t)chunks * IN_F;
    float* bsum = wsum + IN_F;

    colsum_kernel<<<dim3(COLG, chunks), TPB, 0, stream>>>(W, part, rpc);
    combine_kernel<<<33, TPB, 0, stream>>>(part, bias, wsum, bsum, chunks);
    rowdot_kernel<<<NBLK_R, TPB, 0, stream>>>(x, wsum, bsum, out);
}

// Round 6
// 100.328 us; speedup vs baseline: 2.0586x; 1.0041x over previous
//
#include <hip/hip_runtime.h>
#include <hip/hip_cooperative_groups.h>

namespace cg = cooperative_groups;

typedef float f32x4 __attribute__((ext_vector_type(4)));

constexpr int IN_F  = 8192;
constexpr int OUT_F = 8192;
constexpr int BATCH = 4096;
constexpr int TPB   = 256;

// ---- fused cooperative config: 2048 blocks = 8/CU = 32 waves/CU (full) ----
constexpr int NBLK   = 2048;
constexpr int CHUNKS = NBLK / 8;          // 256 row-chunks in phase 1
constexpr int RPC    = OUT_F / CHUNKS;    // 32 rows per chunk
constexpr int ROWS   = BATCH / NBLK;      // 2 batch rows per block in phase 3

// out[b] = ( dot(x[b,:], wsum) + bsum ) / OUT_F,  wsum[i] = sum_o W[o,i]
__global__ __launch_bounds__(TPB, 8) void fused_kernel(
    const float* __restrict__ x, const float* __restrict__ W,
    const float* __restrict__ bias, float* __restrict__ out,
    float* __restrict__ part, float* __restrict__ wsum,
    float* __restrict__ bsum) {

    __shared__ float red[8];
    const int tid = threadIdx.x, blk = blockIdx.x;

    // ---- Phase 1: partial column sums of W (plain cacheable loads).
    //      Consecutive blocks cover contiguous 4 KB column-windows of the
    //      same row-chunk -> contiguous sweeps, L2/L3 friendly. ----
    {
        const int g = blk & 7;            // column group (1024 floats)
        const int c = blk >> 3;           // row chunk
        const f32x4* __restrict__ p = reinterpret_cast<const f32x4*>(W)
            + (long)c * RPC * (IN_F / 4) + g * TPB + tid;
        f32x4 acc = {0.f, 0.f, 0.f, 0.f};
        #pragma unroll 8
        for (int r = 0; r < RPC; ++r)
            acc += p[(long)r * (IN_F / 4)];
        reinterpret_cast<f32x4*>(part)[(long)c * (IN_F / 4) + g * TPB + tid] = acc;
    }

    cg::this_grid().sync();

    // ---- Phase 2: combine partials -> wsum (fixed order, deterministic);
    //      block 32 reduces bias. 33 of 2048 blocks active (~3 us). ----
    if (blk < 32) {
        const int col = blk * TPB + tid;
        float s = 0.f;
        #pragma unroll 8
        for (int c = 0; c < CHUNKS; ++c) s += part[(long)c * IN_F + col];
        wsum[col] = s;
    } else if (blk == 32) {
        float bs = 0.f;
        for (int k = tid; k < OUT_F; k += TPB) bs += bias[k];
        #pragma unroll
        for (int o = 32; o; o >>= 1) bs += __shfl_down(bs, o);
        if ((tid & 63) == 0) red[tid >> 6] = bs;
        __syncthreads();   // block-uniform branch: safe
        if (tid == 0) *bsum = red[0] + red[1] + red[2] + red[3];
    }

    cg::this_grid().sync();

    // ---- Phase 3: 2 rows per block; wsum (32 KB) read from L2, no LDS ----
    {
        const long rowbase = (long)blk * ROWS;
        const f32x4* __restrict__ x4 =
            reinterpret_cast<const f32x4*>(x) + rowbase * (IN_F / 4);
        const f32x4* __restrict__ w4 = reinterpret_cast<const f32x4*>(wsum);
        float s0 = 0.f, s1 = 0.f;
        #pragma unroll
        for (int k = tid; k < IN_F / 4; k += TPB) {   // 8 iters, unrolled
            f32x4 wv = w4[k];
            f32x4 a  = x4[k];
            f32x4 b  = x4[(IN_F / 4) + k];
            s0 += a.x * wv.x + a.y * wv.y + a.z * wv.z + a.w * wv.w;
            s1 += b.x * wv.x + b.y * wv.y + b.z * wv.z + b.w * wv.w;
        }
        #pragma unroll
        for (int o = 32; o; o >>= 1) {
            s0 += __shfl_down(s0, o);
            s1 += __shfl_down(s1, o);
        }
        const int wid = tid >> 6;
        if ((tid & 63) == 0) { red[wid] = s0; red[4 + wid] = s1; }
        __syncthreads();
        if (tid == 0) {
            const float bsv = *bsum;
            out[rowbase]     = (red[0]+red[1]+red[2]+red[3] + bsv) * (1.0f / OUT_F);
            out[rowbase + 1] = (red[4]+red[5]+red[6]+red[7] + bsv) * (1.0f / OUT_F);
        }
    }
}

// ---------------- fallback: proven 3-kernel path (R5, 100.7 us) -------------
constexpr int COLG = IN_F / (TPB * 4);   // 8

__global__ __launch_bounds__(TPB) void colsum_kernel(
    const float* __restrict__ W, float* __restrict__ part, int rpc) {
    const int col4 = blockIdx.x * TPB + threadIdx.x;
    const f32x4* __restrict__ p = reinterpret_cast<const f32x4*>(W)
        + (long)blockIdx.y * rpc * (IN_F / 4) + col4;
    f32x4 acc = {0.f, 0.f, 0.f, 0.f};
    #pragma unroll 8
    for (int r = 0; r < rpc; ++r)
        acc += p[(long)r * (IN_F / 4)];
    reinterpret_cast<f32x4*>(part)[(long)blockIdx.y * (IN_F / 4) + col4] = acc;
}

__global__ __launch_bounds__(TPB) void combine_kernel(
    const float* __restrict__ part, const float* __restrict__ bias,
    float* __restrict__ wsum, float* __restrict__ bsum, int chunks) {
    const int blk = blockIdx.x, tid = threadIdx.x;
    if (blk < 32) {
        const int col = blk * TPB + tid;
        float s = 0.f;
        #pragma unroll 8
        for (int c = 0; c < chunks; ++c) s += part[(long)c * IN_F + col];
        wsum[col] = s;
    } else {
        __shared__ float red[4];
        float bs = 0.f;
        for (int k = tid; k < OUT_F; k += TPB) bs += bias[k];
        #pragma unroll
        for (int o = 32; o; o >>= 1) bs += __shfl_down(bs, o);
        if ((tid & 63) == 0) red[tid >> 6] = bs;
        __syncthreads();
        if (tid == 0) *bsum = red[0] + red[1] + red[2] + red[3];
    }
}

__global__ __launch_bounds__(TPB) void rowdot_kernel(
    const float* __restrict__ x, const float* __restrict__ wsum,
    const float* __restrict__ bsum, float* __restrict__ out) {
    __shared__ float red[8];
    const int tid = threadIdx.x;
    const long rowbase = (long)blockIdx.x * ROWS;
    const f32x4* __restrict__ x4 =
        reinterpret_cast<const f32x4*>(x) + rowbase * (IN_F / 4);
    const f32x4* __restrict__ w4 = reinterpret_cast<const f32x4*>(wsum);
    float s0 = 0.f, s1 = 0.f;
    #pragma unroll
    for (int k = tid; k < IN_F / 4; k += TPB) {
        f32x4 wv = w4[k];
        f32x4 a  = x4[k];
        f32x4 b  = x4[(IN_F / 4) + k];
        s0 += a.x * wv.x + a.y * wv.y + a.z * wv.z + a.w * wv.w;
        s1 += b.x * wv.x + b.y * wv.y + b.z * wv.z + b.w * wv.w;
    }
    #pragma unroll
    for (int o = 32; o; o >>= 1) {
        s0 += __shfl_down(s0, o);
        s1 += __shfl_down(s1, o);
    }
    const int wid = tid >> 6;
    if ((tid & 63) == 0) { red[wid] = s0; red[4 + wid] = s1; }
    __syncthreads();
    if (tid == 0) {
        const float bsv = *bsum;
        out[rowbase]     = (red[0]+red[1]+red[2]+red[3] + bsv) * (1.0f / OUT_F);
        out[rowbase + 1] = (red[4]+red[5]+red[6]+red[7] + bsv) * (1.0f / OUT_F);
    }
}

extern "C" void kernel_launch(void* const* d_in, const int* in_sizes, int n_in,
                              void* d_out, int out_size, void* d_ws, size_t ws_size,
                              hipStream_t stream) {
    const float* x    = (const float*)d_in[0];  // [BATCH, IN_F]
    const float* W    = (const float*)d_in[1];  // [OUT_F, IN_F]
    const float* bias = (const float*)d_in[2];  // [OUT_F]
    float*       out  = (float*)d_out;          // [BATCH]

    // ws: [CHUNKS][IN_F] partials (8 MB) | [IN_F] wsum | [1] bsum
    float* part = (float*)d_ws;
    float* wsum = part + (size_t)CHUNKS * IN_F;
    float* bsum = wsum + IN_F;

    // Capture-safe host queries -> deterministic path choice.
    int dev = 0;    (void)hipGetDevice(&dev);
    int coop = 0;   (void)hipDeviceGetAttribute(&coop, hipDeviceAttributeCooperativeLaunch, dev);
    int ncu = 0;    (void)hipDeviceGetAttribute(&ncu, hipDeviceAttributeMultiprocessorCount, dev);
    int maxblk = 0;
    (void)hipOccupancyMaxActiveBlocksPerMultiprocessor(&maxblk, fused_kernel, TPB, 0);

    if (coop && (long)maxblk * ncu >= NBLK &&
        ((size_t)CHUNKS * IN_F + IN_F + 16) * sizeof(float) <= ws_size) {
        void* args[] = {(void*)&x, (void*)&W, (void*)&bias, (void*)&out,
                        (void*)&part, (void*)&wsum, (void*)&bsum};
        hipError_t err = hipLaunchCooperativeKernel(
            (const void*)fused_kernel, dim3(NBLK), dim3(TPB), args, 0, stream);
        if (err == hipSuccess) return;
    }

    // fallback (proven): three kernels
    int chunks = 256;
    while (chunks > 1 &&
           ((size_t)chunks * IN_F + IN_F + 16) * sizeof(float) > ws_size)
        chunks >>= 1;
    const int rpc = OUT_F / chunks;
    float* wsumF = part + (size_t)chunks * IN_F;
    float* bsumF = wsumF + IN_F;
    colsum_kernel<<<dim3(COLG, chunks), TPB, 0, stream>>>(W, part, rpc);
    combine_kernel<<<33, TPB, 0, stream>>>(part, bias, wsumF, bsumF, chunks);
    rowdot_kernel<<<BATCH / ROWS, TPB, 0, stream>>>(x, wsumF, bsumF, out);
}

// Round 7
// 96.411 us; speedup vs baseline: 2.1422x; 1.0406x over previous
//
#include <hip/hip_runtime.h>

typedef float f32x4 __attribute__((ext_vector_type(4)));

constexpr int IN_F  = 8192;
constexpr int OUT_F = 8192;
constexpr int BATCH = 4096;
constexpr int TPB   = 256;
constexpr int S4    = IN_F / 4;          // f32x4 stride of one W row

constexpr int CHUNKS = 256;              // row-chunks in colsum
constexpr int RPC    = OUT_F / CHUNKS;   // 32 rows per chunk
constexpr int COLG   = IN_F / (TPB * 4); // 8 column groups

// ---------------------------------------------------------------------------
// Kernel A: partial column sums of W.  grid = (8, 256) = 2048 blocks (8/CU).
//   Dual accumulators break the serial add chain; unroll 8 x 2 loads = 16
//   outstanding 16B loads per scheduling batch. Plain cacheable loads (L3
//   serves ~half the stream across graph replays — R6 FETCH_SIZE evidence).
// ---------------------------------------------------------------------------
__global__ __launch_bounds__(TPB) void colsum_kernel(
    const float* __restrict__ W, float* __restrict__ part, int rpc) {
    const int col4 = blockIdx.x * TPB + threadIdx.x;
    const f32x4* __restrict__ p = reinterpret_cast<const f32x4*>(W)
        + (long)blockIdx.y * rpc * S4 + col4;
    f32x4 a0 = {0.f, 0.f, 0.f, 0.f}, a1 = {0.f, 0.f, 0.f, 0.f};
    #pragma unroll 8
    for (int r = 0; r < rpc; r += 2) {       // rpc is even
        a0 += p[(long)r * S4];
        a1 += p[(long)(r + 1) * S4];
    }
    reinterpret_cast<f32x4*>(part)[(long)blockIdx.y * S4 + col4] = a0 + a1;
}

// ---------------------------------------------------------------------------
// Kernel B: combine partials -> wsum, PARALLEL: 256 blocks x 32 columns each
//   (8 chunk-slices of 32 in parallel per block, LDS reduce — fixed order,
//   deterministic). Block 256 reduces bias -> bsum.
//   grid = 257, block = 256.
// ---------------------------------------------------------------------------
__global__ __launch_bounds__(TPB) void combine_kernel(
    const float* __restrict__ part, const float* __restrict__ bias,
    float* __restrict__ wsum, float* __restrict__ bsum) {
    const int blk = blockIdx.x, tid = threadIdx.x;
    if (blk < 256) {
        __shared__ float lds[TPB];
        const int col   = blk * 32 + (tid & 31);   // column within this block's window
        const int slice = tid >> 5;                // 8 slices of 32 chunks
        float s = 0.f;
        #pragma unroll 8
        for (int k = 0; k < CHUNKS / 8; ++k)
            s += part[(long)(slice * (CHUNKS / 8) + k) * IN_F + col];
        lds[tid] = s;
        __syncthreads();
        if (tid < 32) {
            float t = 0.f;
            #pragma unroll
            for (int sl = 0; sl < 8; ++sl) t += lds[sl * 32 + tid];
            wsum[blk * 32 + tid] = t;
        }
    } else {
        __shared__ float red[4];
        float bs = 0.f;
        for (int k = tid; k < OUT_F; k += TPB) bs += bias[k];
        #pragma unroll
        for (int o = 32; o; o >>= 1) bs += __shfl_down(bs, o);
        if ((tid & 63) == 0) red[tid >> 6] = bs;
        __syncthreads();
        if (tid == 0) *bsum = red[0] + red[1] + red[2] + red[3];
    }
}

// ---------------------------------------------------------------------------
// Kernel C: out[b] = (dot(x[b,:], wsum) + bsum) / OUT_F
//   grid = 2048 (8/CU), 2 rows per block; wsum is L2-resident (no LDS).
// ---------------------------------------------------------------------------
constexpr int NBLK_R = 2048;
constexpr int ROWS_R = BATCH / NBLK_R;   // 2

__global__ __launch_bounds__(TPB) void rowdot_kernel(
    const float* __restrict__ x, const float* __restrict__ wsum,
    const float* __restrict__ bsum, float* __restrict__ out) {
    __shared__ float red[8];
    const int tid = threadIdx.x;
    const long rowbase = (long)blockIdx.x * ROWS_R;
    const f32x4* __restrict__ x4 =
        reinterpret_cast<const f32x4*>(x) + rowbase * S4;
    const f32x4* __restrict__ w4 = reinterpret_cast<const f32x4*>(wsum);

    float s0 = 0.f, s1 = 0.f;
    #pragma unroll
    for (int k = tid; k < S4; k += TPB) {    // 8 iterations, fully unrolled
        f32x4 wv = w4[k];
        f32x4 a  = x4[k];
        f32x4 b  = x4[S4 + k];
        s0 += a.x * wv.x + a.y * wv.y + a.z * wv.z + a.w * wv.w;
        s1 += b.x * wv.x + b.y * wv.y + b.z * wv.z + b.w * wv.w;
    }
    #pragma unroll
    for (int o = 32; o; o >>= 1) {
        s0 += __shfl_down(s0, o);
        s1 += __shfl_down(s1, o);
    }
    const int wid = tid >> 6;
    if ((tid & 63) == 0) { red[wid] = s0; red[4 + wid] = s1; }
    __syncthreads();
    if (tid == 0) {
        const float bsv = *bsum;
        out[rowbase]     = (red[0] + red[1] + red[2] + red[3] + bsv) * (1.0f / OUT_F);
        out[rowbase + 1] = (red[4] + red[5] + red[6] + red[7] + bsv) * (1.0f / OUT_F);
    }
}

// ---------------- fallback (small ws): generic serial combine ---------------
__global__ __launch_bounds__(TPB) void combine_generic_kernel(
    const float* __restrict__ part, const float* __restrict__ bias,
    float* __restrict__ wsum, float* __restrict__ bsum, int chunks) {
    const int blk = blockIdx.x, tid = threadIdx.x;
    if (blk < 32) {
        const int col = blk * TPB + tid;
        float s = 0.f;
        #pragma unroll 8
        for (int c = 0; c < chunks; ++c) s += part[(long)c * IN_F + col];
        wsum[col] = s;
    } else {
        __shared__ float red[4];
        float bs = 0.f;
        for (int k = tid; k < OUT_F; k += TPB) bs += bias[k];
        #pragma unroll
        for (int o = 32; o; o >>= 1) bs += __shfl_down(bs, o);
        if ((tid & 63) == 0) red[tid >> 6] = bs;
        __syncthreads();
        if (tid == 0) *bsum = red[0] + red[1] + red[2] + red[3];
    }
}

extern "C" void kernel_launch(void* const* d_in, const int* in_sizes, int n_in,
                              void* d_out, int out_size, void* d_ws, size_t ws_size,
                              hipStream_t stream) {
    const float* x    = (const float*)d_in[0];  // [BATCH, IN_F]
    const float* W    = (const float*)d_in[1];  // [OUT_F, IN_F]
    const float* bias = (const float*)d_in[2];  // [OUT_F]
    float*       out  = (float*)d_out;          // [BATCH]

    if (((size_t)CHUNKS * IN_F + IN_F + 16) * sizeof(float) <= ws_size) {
        // main path: 256 chunks, parallel combine
        float* part = (float*)d_ws;
        float* wsum = part + (size_t)CHUNKS * IN_F;
        float* bsum = wsum + IN_F;
        colsum_kernel<<<dim3(COLG, CHUNKS), TPB, 0, stream>>>(W, part, RPC);
        combine_kernel<<<257, TPB, 0, stream>>>(part, bias, wsum, bsum);
        rowdot_kernel<<<NBLK_R, TPB, 0, stream>>>(x, wsum, bsum, out);
    } else {
        // fallback: shrink chunks, serial combine
        int chunks = 128;
        while (chunks > 1 &&
               ((size_t)chunks * IN_F + IN_F + 16) * sizeof(float) > ws_size)
            chunks >>= 1;
        float* part = (float*)d_ws;
        float* wsum = part + (size_t)chunks * IN_F;
        float* bsum = wsum + IN_F;
        colsum_kernel<<<dim3(COLG, chunks), TPB, 0, stream>>>(W, part, OUT_F / chunks);
        combine_generic_kernel<<<33, TPB, 0, stream>>>(part, bias, wsum, bsum, chunks);
        rowdot_kernel<<<NBLK_R, TPB, 0, stream>>>(x, wsum, bsum, out);
    }
}

// Round 8
// 95.830 us; speedup vs baseline: 2.1552x; 1.0061x over previous
//
#include <hip/hip_runtime.h>

typedef float f32x4 __attribute__((ext_vector_type(4)));

constexpr int IN_F  = 8192;
constexpr int OUT_F = 8192;
constexpr int BATCH = 4096;
constexpr int TPB   = 256;
constexpr int S4    = IN_F / 4;            // f32x4 per row

// ---- main (contiguous) path ----
constexpr int CHUNKS = 1024;               // 8 rows per chunk
constexpr int RPCH   = OUT_F / CHUNKS;     // 8
// ---- fallback (strided) path ----
constexpr int CHUNKS_FB = 256;
constexpr int COLG      = IN_F / (TPB * 4);   // 8

// ---------------------------------------------------------------------------
// Kernel A (main): column sums, CONTIGUOUS streaming.
//   Block c owns rows [8c, 8c+8) = 256 KB of W, read fully sequentially.
//   Each thread accumulates 8 f32x4 column-slots (static indices -> VGPRs).
//   grid = 1024 (4/CU), block = 256, <=128 VGPR via launch_bounds(256,4).
// ---------------------------------------------------------------------------
__global__ __launch_bounds__(TPB, 4) void colsum_contig_kernel(
    const float* __restrict__ W, float* __restrict__ part) {
    const int tid = threadIdx.x, c = blockIdx.x;
    const f32x4* __restrict__ p =
        reinterpret_cast<const f32x4*>(W) + (long)c * RPCH * S4;
    f32x4 acc[8] = {};
    #pragma unroll
    for (int r = 0; r < RPCH; ++r) {
        #pragma unroll
        for (int j = 0; j < 8; ++j)
            acc[j] += p[(long)r * S4 + j * TPB + tid];
    }
    f32x4* o = reinterpret_cast<f32x4*>(part) + (long)c * S4;
    #pragma unroll
    for (int j = 0; j < 8; ++j) o[j * TPB + tid] = acc[j];
}

// ---------------------------------------------------------------------------
// Kernel B (main): combine 1024 partials -> wsum. 128 blocks x 64 columns,
//   4 slices of 256 chunks each (wave-uniform slice -> 256 B contiguous
//   segments, L2/L3-resident). Fixed order: deterministic. blk 128 = bias.
//   grid = 129, block = 256.
// ---------------------------------------------------------------------------
__global__ __launch_bounds__(TPB) void combine_c_kernel(
    const float* __restrict__ part, const float* __restrict__ bias,
    float* __restrict__ wsum, float* __restrict__ bsum) {
    const int blk = blockIdx.x, tid = threadIdx.x;
    if (blk < IN_F / 64) {
        __shared__ float lds[TPB];
        const int col = blk * 64 + (tid & 63);
        const int sl  = tid >> 6;              // 4 slices x 256 chunks
        float s = 0.f;
        #pragma unroll 8
        for (int k = 0; k < CHUNKS / 4; ++k)
            s += part[(long)(sl * (CHUNKS / 4) + k) * IN_F + col];
        lds[tid] = s;
        __syncthreads();
        if (tid < 64)
            wsum[blk * 64 + tid] =
                lds[tid] + lds[64 + tid] + lds[128 + tid] + lds[192 + tid];
    } else {
        __shared__ float red[4];
        float bs = 0.f;
        for (int k = tid; k < OUT_F; k += TPB) bs += bias[k];
        #pragma unroll
        for (int o = 32; o; o >>= 1) bs += __shfl_down(bs, o);
        if ((tid & 63) == 0) red[tid >> 6] = bs;
        __syncthreads();
        if (tid == 0) *bsum = red[0] + red[1] + red[2] + red[3];
    }
}

// ---------------------------------------------------------------------------
// Kernel C: out[b] = (dot(x[b,:], wsum) + bsum) / OUT_F
//   1 row per block, 4096 blocks (16/CU): max TLP, short chains, small tail.
//   wsum is L2-resident (no LDS staging).
// ---------------------------------------------------------------------------
__global__ __launch_bounds__(TPB) void rowdot1_kernel(
    const float* __restrict__ x, const float* __restrict__ wsum,
    const float* __restrict__ bsum, float* __restrict__ out) {
    __shared__ float red[4];
    const int tid = threadIdx.x;
    const long b  = blockIdx.x;
    const f32x4* __restrict__ x4 = reinterpret_cast<const f32x4*>(x) + b * S4;
    const f32x4* __restrict__ w4 = reinterpret_cast<const f32x4*>(wsum);
    float s = 0.f;
    #pragma unroll
    for (int j = 0; j < 8; ++j) {
        f32x4 a = x4[j * TPB + tid];
        f32x4 w = w4[j * TPB + tid];
        s += a.x * w.x + a.y * w.y + a.z * w.z + a.w * w.w;
    }
    #pragma unroll
    for (int o = 32; o; o >>= 1) s += __shfl_down(s, o);
    if ((tid & 63) == 0) red[tid >> 6] = s;
    __syncthreads();
    if (tid == 0)
        out[b] = (red[0] + red[1] + red[2] + red[3] + *bsum) * (1.0f / OUT_F);
}

// ---------------- fallback kernels (ws too small): proven R7 path -----------
__global__ __launch_bounds__(TPB) void colsum_strided_kernel(
    const float* __restrict__ W, float* __restrict__ part, int rpc) {
    const int col4 = blockIdx.x * TPB + threadIdx.x;
    const f32x4* __restrict__ p = reinterpret_cast<const f32x4*>(W)
        + (long)blockIdx.y * rpc * S4 + col4;
    f32x4 a0 = {0.f,0.f,0.f,0.f}, a1 = {0.f,0.f,0.f,0.f};
    #pragma unroll 8
    for (int r = 0; r < rpc; r += 2) {
        a0 += p[(long)r * S4];
        a1 += p[(long)(r + 1) * S4];
    }
    reinterpret_cast<f32x4*>(part)[(long)blockIdx.y * S4 + col4] = a0 + a1;
}

__global__ __launch_bounds__(TPB) void combine_fb_kernel(
    const float* __restrict__ part, const float* __restrict__ bias,
    float* __restrict__ wsum, float* __restrict__ bsum, int chunks) {
    const int blk = blockIdx.x, tid = threadIdx.x;
    if (blk < 32) {
        const int col = blk * TPB + tid;
        float s = 0.f;
        #pragma unroll 8
        for (int c = 0; c < chunks; ++c) s += part[(long)c * IN_F + col];
        wsum[col] = s;
    } else {
        __shared__ float red[4];
        float bs = 0.f;
        for (int k = tid; k < OUT_F; k += TPB) bs += bias[k];
        #pragma unroll
        for (int o = 32; o; o >>= 1) bs += __shfl_down(bs, o);
        if ((tid & 63) == 0) red[tid >> 6] = bs;
        __syncthreads();
        if (tid == 0) *bsum = red[0] + red[1] + red[2] + red[3];
    }
}

extern "C" void kernel_launch(void* const* d_in, const int* in_sizes, int n_in,
                              void* d_out, int out_size, void* d_ws, size_t ws_size,
                              hipStream_t stream) {
    const float* x    = (const float*)d_in[0];  // [BATCH, IN_F]
    const float* W    = (const float*)d_in[1];  // [OUT_F, IN_F]
    const float* bias = (const float*)d_in[2];  // [OUT_F]
    float*       out  = (float*)d_out;          // [BATCH]

    if (((size_t)CHUNKS * IN_F + IN_F + 16) * sizeof(float) <= ws_size) {
        // main path: contiguous colsum (1024 chunks, 32 MB partials)
        float* part = (float*)d_ws;
        float* wsum = part + (size_t)CHUNKS * IN_F;
        float* bsum = wsum + IN_F;
        colsum_contig_kernel<<<CHUNKS, TPB, 0, stream>>>(W, part);
        combine_c_kernel<<<IN_F / 64 + 1, TPB, 0, stream>>>(part, bias, wsum, bsum);
        rowdot1_kernel<<<BATCH, TPB, 0, stream>>>(x, wsum, bsum, out);
    } else {
        // fallback: strided colsum, shrink chunks to fit ws
        int chunks = CHUNKS_FB;
        while (chunks > 1 &&
               ((size_t)chunks * IN_F + IN_F + 16) * sizeof(float) > ws_size)
            chunks >>= 1;
        float* part = (float*)d_ws;
        float* wsum = part + (size_t)chunks * IN_F;
        float* bsum = wsum + IN_F;
        colsum_strided_kernel<<<dim3(COLG, chunks), TPB, 0, stream>>>(
            W, part, OUT_F / chunks);
        combine_fb_kernel<<<33, TPB, 0, stream>>>(part, bias, wsum, bsum, chunks);
        rowdot1_kernel<<<BATCH, TPB, 0, stream>>>(x, wsum, bsum, out);
    }
}